// Round 2
// baseline (887.236 us; speedup 1.0000x reference)
//
#include <hip/hip_runtime.h>

// TransformerClassification: 2-layer PyG TransformerConv GNN on MI355X.
// Layer1: IN=128 -> H=4 heads x CH=16 (concat -> 64), edge_dim=2, +skip, ELU.
// Layer2: 64 -> 7, heads=1, +skip.
// ALL float tensors are float32 on device (verified via npz sizes); edge_index int32 [2,E].

#define N_NODES 50000
#define N_EDGES 800000
#define IN_F    128
#define HC      64      // heads*ch layer1
#define NH      4
#define CH      16
#define OUTF    7

// order-preserving float<->uint encoding for atomicMax on floats
__device__ __forceinline__ unsigned encf(float f) {
    unsigned u = __float_as_uint(f);
    return (u & 0x80000000u) ? ~u : (u | 0x80000000u);
}
__device__ __forceinline__ float decf(unsigned u) {
    return (u & 0x80000000u) ? __uint_as_float(u & 0x7FFFFFFFu)
                             : __uint_as_float(~u);
}

// ---------------------------------------------------------------- init
__global__ __launch_bounds__(256) void init_kernel(
    float* out1, unsigned* amax1, float* denom1,
    float* out2, unsigned* amax2, float* denom2)
{
    int i = blockIdx.x * 256 + threadIdx.x;
    const unsigned negenc = encf(-3.402823466e+38f);
    if (i < N_NODES * HC)   out1[i] = 0.f;
    if (i < N_NODES * NH)   { amax1[i] = negenc; denom1[i] = 0.f; }
    if (i < N_NODES * OUTF) out2[i] = 0.f;
    if (i < N_NODES)        { amax2[i] = negenc; denom2[i] = 0.f; }
}

// ---------------------------------------------------------------- layer1 node projections
// 16 nodes per block, 64 threads (one per output column).
// W rows loaded once per block, reused across 16 nodes.
#define P1_NB 16
__global__ __launch_bounds__(64) void proj1_kernel(
    const float* __restrict__ x,
    const float* __restrict__ Wq, const float* __restrict__ bq,
    const float* __restrict__ Wk, const float* __restrict__ bk,
    const float* __restrict__ Wv, const float* __restrict__ bv,
    const float* __restrict__ Ws, const float* __restrict__ bs,
    float* __restrict__ q1, float* __restrict__ k1,
    float* __restrict__ v1, float* __restrict__ s1)
{
    __shared__ float xs[P1_NB][IN_F];
    const int t  = threadIdx.x;          // 0..63 = output column
    const int n0 = blockIdx.x * P1_NB;

    for (int j = t; j < P1_NB * IN_F; j += 64)
        xs[j >> 7][j & 127] = x[(size_t)n0 * IN_F + j];
    __syncthreads();

    float aq[P1_NB], ak[P1_NB], av[P1_NB], as_[P1_NB];
#pragma unroll
    for (int n = 0; n < P1_NB; n++) { aq[n] = ak[n] = av[n] = as_[n] = 0.f; }

    for (int i = 0; i < IN_F; i++) {
        float wq = Wq[i * HC + t];
        float wk = Wk[i * HC + t];
        float wv = Wv[i * HC + t];
        float ws = Ws[i * HC + t];
#pragma unroll
        for (int n = 0; n < P1_NB; n++) {
            float xv = xs[n][i];
            aq[n] += xv * wq; ak[n] += xv * wk;
            av[n] += xv * wv; as_[n] += xv * ws;
        }
    }
    float bqv = bq[t], bkv = bk[t], bvv = bv[t], bsv = bs[t];
#pragma unroll
    for (int n = 0; n < P1_NB; n++) {
        size_t o = (size_t)(n0 + n) * HC + t;
        q1[o] = aq[n] + bqv; k1[o] = ak[n] + bkv;
        v1[o] = av[n] + bvv; s1[o] = as_[n] + bsv;
    }
}

// ---------------------------------------------------------------- layer1 edge pass 1: logits + segment max
// one wave (64 lanes) per edge; lane = channel, head = lane>>4
__global__ __launch_bounds__(256) void edge_logits1(
    const int* __restrict__ ei, const float* __restrict__ ea,
    const float* __restrict__ We,
    const float* __restrict__ q1, const float* __restrict__ k1,
    float* __restrict__ alpha1, unsigned* __restrict__ amax1)
{
    int wid  = (blockIdx.x * 256 + threadIdx.x) >> 6;
    int lane = threadIdx.x & 63;
    if (wid >= N_EDGES) return;
    int src = ei[wid], dst = ei[N_EDGES + wid];

    float ea0 = ea[(size_t)wid * 2], ea1 = ea[(size_t)wid * 2 + 1];
    float ec  = ea0 * We[lane] + ea1 * We[HC + lane];

    float p = q1[(size_t)dst * HC + lane] * (k1[(size_t)src * HC + lane] + ec);
    p += __shfl_xor(p, 1); p += __shfl_xor(p, 2);
    p += __shfl_xor(p, 4); p += __shfl_xor(p, 8);   // 16-lane (head) sum
    if ((lane & 15) == 0) {
        float logit = p * 0.25f;                    // 1/sqrt(16)
        int h = lane >> 4;
        alpha1[(size_t)wid * NH + h] = logit;
        atomicMax(amax1 + (size_t)dst * NH + h, encf(logit));
    }
}

// ---------------------------------------------------------------- layer1 edge pass 2: exp + segment sum
__global__ __launch_bounds__(256) void edge_exp1(
    const int* __restrict__ ei,
    float* __restrict__ alpha1, const unsigned* __restrict__ amax1,
    float* __restrict__ denom1)
{
    int idx = blockIdx.x * 256 + threadIdx.x;
    if (idx >= N_EDGES * NH) return;
    int e = idx >> 2, h = idx & 3;
    int dst = ei[N_EDGES + e];
    float ex = expf(alpha1[idx] - decf(amax1[(size_t)dst * NH + h]));
    alpha1[idx] = ex;
    atomicAdd(denom1 + (size_t)dst * NH + h, ex);
}

// ---------------------------------------------------------------- layer1 edge pass 3: weighted accumulate
__global__ __launch_bounds__(256) void edge_acc1(
    const int* __restrict__ ei, const float* __restrict__ ea,
    const float* __restrict__ We,
    const float* __restrict__ v1,
    const float* __restrict__ alpha1, const float* __restrict__ denom1,
    float* __restrict__ out1)
{
    int wid  = (blockIdx.x * 256 + threadIdx.x) >> 6;
    int lane = threadIdx.x & 63;
    if (wid >= N_EDGES) return;
    int src = ei[wid], dst = ei[N_EDGES + wid];
    int h = lane >> 4;

    float ex = alpha1[(size_t)wid * NH + h];
    float dn = denom1[(size_t)dst * NH + h];
    float a  = ex / fmaxf(dn, 1e-16f);

    float ea0 = ea[(size_t)wid * 2], ea1 = ea[(size_t)wid * 2 + 1];
    float ec  = ea0 * We[lane] + ea1 * We[HC + lane];

    float v = v1[(size_t)src * HC + lane] + ec;
    atomicAdd(out1 + (size_t)dst * HC + lane, v * a);
}

// ---------------------------------------------------------------- ELU(att + skip) -> h
__global__ __launch_bounds__(256) void elu_kernel(
    const float* __restrict__ out1, const float* __restrict__ s1,
    float* __restrict__ h)
{
    int i = blockIdx.x * 256 + threadIdx.x;
    if (i >= N_NODES * HC) return;
    float v = out1[i] + s1[i];
    h[i] = v > 0.f ? v : expm1f(v);
}

// ---------------------------------------------------------------- layer2 node projections (64 -> 7, x4 matrices)
// 8 nodes per block of 256; 32 lanes per node, 28 active (4 matrices x 7 cols)
__global__ __launch_bounds__(256) void proj2_kernel(
    const float* __restrict__ h,
    const float* __restrict__ Wq, const float* __restrict__ bq,
    const float* __restrict__ Wk, const float* __restrict__ bk,
    const float* __restrict__ Wv, const float* __restrict__ bv,
    const float* __restrict__ Ws, const float* __restrict__ bs,
    float* __restrict__ q2, float* __restrict__ k2,
    float* __restrict__ v2, float* __restrict__ s2)
{
    __shared__ float hs[8][HC];
    const int t  = threadIdx.x;
    const int n0 = blockIdx.x * 8;
    for (int j = t; j < 8 * HC; j += 256) {
        size_t g = (size_t)n0 * HC + j;
        if (g < (size_t)N_NODES * HC) hs[j >> 6][j & 63] = h[g];
    }
    __syncthreads();

    int ni = t >> 5, j = t & 31;
    int n = n0 + ni;
    if (j < 28 && n < N_NODES) {
        int m = j / 7, c = j % 7;
        const float* W = (m == 0) ? Wq : (m == 1) ? Wk : (m == 2) ? Wv : Ws;
        const float* B = (m == 0) ? bq : (m == 1) ? bk : (m == 2) ? bv : bs;
        float acc = B[c];
        for (int i = 0; i < HC; i++)
            acc += hs[ni][i] * W[i * OUTF + c];
        float* dstp = (m == 0) ? q2 : (m == 1) ? k2 : (m == 2) ? v2 : s2;
        dstp[(size_t)n * OUTF + c] = acc;
    }
}

// ---------------------------------------------------------------- layer2 edge passes (thread per edge, heads=1, C=7)
__global__ __launch_bounds__(256) void edge_logits2(
    const int* __restrict__ ei,
    const float* __restrict__ q2, const float* __restrict__ k2,
    float* __restrict__ alpha2, unsigned* __restrict__ amax2)
{
    int e = blockIdx.x * 256 + threadIdx.x;
    if (e >= N_EDGES) return;
    int src = ei[e], dst = ei[N_EDGES + e];
    float acc = 0.f;
#pragma unroll
    for (int c = 0; c < OUTF; c++)
        acc += q2[(size_t)dst * OUTF + c] * k2[(size_t)src * OUTF + c];
    float logit = acc * 0.37796447300922725f;   // 1/sqrt(7)
    alpha2[e] = logit;
    atomicMax(amax2 + dst, encf(logit));
}

__global__ __launch_bounds__(256) void edge_exp2(
    const int* __restrict__ ei,
    float* __restrict__ alpha2, const unsigned* __restrict__ amax2,
    float* __restrict__ denom2)
{
    int e = blockIdx.x * 256 + threadIdx.x;
    if (e >= N_EDGES) return;
    int dst = ei[N_EDGES + e];
    float ex = expf(alpha2[e] - decf(amax2[dst]));
    alpha2[e] = ex;
    atomicAdd(denom2 + dst, ex);
}

__global__ __launch_bounds__(256) void edge_acc2(
    const int* __restrict__ ei,
    const float* __restrict__ v2,
    const float* __restrict__ alpha2, const float* __restrict__ denom2,
    float* __restrict__ out2)
{
    int e = blockIdx.x * 256 + threadIdx.x;
    if (e >= N_EDGES) return;
    int src = ei[e], dst = ei[N_EDGES + e];
    float a = alpha2[e] / fmaxf(denom2[dst], 1e-16f);
#pragma unroll
    for (int c = 0; c < OUTF; c++)
        atomicAdd(out2 + (size_t)dst * OUTF + c,
                  v2[(size_t)src * OUTF + c] * a);
}

// ---------------------------------------------------------------- final add + f32 store
__global__ __launch_bounds__(256) void final_kernel(
    const float* __restrict__ out2, const float* __restrict__ s2,
    float* __restrict__ out)
{
    int i = blockIdx.x * 256 + threadIdx.x;
    if (i >= N_NODES * OUTF) return;
    out[i] = out2[i] + s2[i];
}

// ----------------------------------------------------------------
extern "C" void kernel_launch(void* const* d_in, const int* in_sizes, int n_in,
                              void* d_out, int out_size, void* d_ws, size_t ws_size,
                              hipStream_t stream)
{
    const float* x    = (const float*)d_in[0];
    const float* ea   = (const float*)d_in[1];
    const int*   ei   = (const int*)d_in[2];
    const float* Wq1  = (const float*)d_in[3];
    const float* bq1  = (const float*)d_in[4];
    const float* Wk1  = (const float*)d_in[5];
    const float* bk1  = (const float*)d_in[6];
    const float* Wv1  = (const float*)d_in[7];
    const float* bv1  = (const float*)d_in[8];
    const float* We1  = (const float*)d_in[9];
    const float* Ws1  = (const float*)d_in[10];
    const float* bs1  = (const float*)d_in[11];
    const float* Wq2  = (const float*)d_in[12];
    const float* bq2  = (const float*)d_in[13];
    const float* Wk2  = (const float*)d_in[14];
    const float* bk2  = (const float*)d_in[15];
    const float* Wv2  = (const float*)d_in[16];
    const float* bv2  = (const float*)d_in[17];
    const float* Ws2  = (const float*)d_in[18];
    const float* bs2  = (const float*)d_in[19];
    float* out = (float*)d_out;

    // workspace layout (all f32 / u32), ~89 MB
    float* ws = (float*)d_ws;
    float*    q1     = ws;                         // N*64
    float*    k1     = q1 + N_NODES * HC;
    float*    v1     = k1 + N_NODES * HC;
    float*    s1     = v1 + N_NODES * HC;
    float*    out1   = s1 + N_NODES * HC;
    float*    alpha1 = out1 + N_NODES * HC;        // E*4
    unsigned* amax1  = (unsigned*)(alpha1 + (size_t)N_EDGES * NH);  // N*4
    float*    denom1 = (float*)(amax1 + N_NODES * NH);              // N*4
    float*    q2     = denom1 + N_NODES * NH;      // N*7
    float*    k2     = q2 + N_NODES * OUTF;
    float*    v2     = k2 + N_NODES * OUTF;
    float*    s2     = v2 + N_NODES * OUTF;
    float*    out2   = s2 + N_NODES * OUTF;
    float*    alpha2 = out2 + N_NODES * OUTF;      // E
    unsigned* amax2  = (unsigned*)(alpha2 + N_EDGES);               // N
    float*    denom2 = (float*)(amax2 + N_NODES);                   // N
    float*    hbuf   = q1;  // reuse q1 after layer1 edge passes

    init_kernel<<<(N_NODES * HC + 255) / 256, 256, 0, stream>>>(
        out1, amax1, denom1, out2, amax2, denom2);

    proj1_kernel<<<N_NODES / P1_NB, 64, 0, stream>>>(
        x, Wq1, bq1, Wk1, bk1, Wv1, bv1, Ws1, bs1, q1, k1, v1, s1);

    int ewave_blocks = (N_EDGES + 3) / 4;          // 4 waves/block, 1 edge/wave
    edge_logits1<<<ewave_blocks, 256, 0, stream>>>(ei, ea, We1, q1, k1, alpha1, amax1);
    edge_exp1<<<(N_EDGES * NH + 255) / 256, 256, 0, stream>>>(ei, alpha1, amax1, denom1);
    edge_acc1<<<ewave_blocks, 256, 0, stream>>>(ei, ea, We1, v1, alpha1, denom1, out1);

    elu_kernel<<<(N_NODES * HC + 255) / 256, 256, 0, stream>>>(out1, s1, hbuf);

    proj2_kernel<<<(N_NODES + 7) / 8, 256, 0, stream>>>(
        hbuf, Wq2, bq2, Wk2, bk2, Wv2, bv2, Ws2, bs2, q2, k2, v2, s2);

    int eth_blocks = (N_EDGES + 255) / 256;
    edge_logits2<<<eth_blocks, 256, 0, stream>>>(ei, q2, k2, alpha2, amax2);
    edge_exp2<<<eth_blocks, 256, 0, stream>>>(ei, alpha2, amax2, denom2);
    edge_acc2<<<eth_blocks, 256, 0, stream>>>(ei, v2, alpha2, denom2, out2);

    final_kernel<<<(N_NODES * OUTF + 255) / 256, 256, 0, stream>>>(out2, s2, out);
}

// Round 4
// 500.134 us; speedup vs baseline: 1.7740x; 1.7740x over previous
//
#include <hip/hip_runtime.h>

// TransformerClassification: 2-layer PyG TransformerConv GNN on MI355X.
// Round 4 == round 3 resubmit (bench infra ran out of /tmp space; no signal).
// dst-centric restructure: counting-sort edges by dst once per launch,
// then one wave per destination node with online softmax in registers.
// Eliminates all float atomics (edge_acc2 alone was 288us of atomic write-amp).

#define N_NODES 50000
#define N_EDGES 800000
#define IN_F    128
#define HC      64      // heads*ch layer1
#define NH      4
#define CH      16
#define OUTF    7

// ---------------------------------------------------------------- init: zero the histogram
__global__ __launch_bounds__(256) void init_kernel(int* __restrict__ count)
{
    int i = blockIdx.x * 256 + threadIdx.x;
    if (i < N_NODES) count[i] = 0;
}

// ---------------------------------------------------------------- layer1 node projections
// 16 nodes per block, 64 threads (one per output column).
#define P1_NB 16
__global__ __launch_bounds__(64) void proj1_kernel(
    const float* __restrict__ x,
    const float* __restrict__ Wq, const float* __restrict__ bq,
    const float* __restrict__ Wk, const float* __restrict__ bk,
    const float* __restrict__ Wv, const float* __restrict__ bv,
    const float* __restrict__ Ws, const float* __restrict__ bs,
    float* __restrict__ q1, float* __restrict__ k1,
    float* __restrict__ v1, float* __restrict__ s1)
{
    __shared__ float xs[P1_NB][IN_F];
    const int t  = threadIdx.x;          // 0..63 = output column
    const int n0 = blockIdx.x * P1_NB;

    for (int j = t; j < P1_NB * IN_F; j += 64)
        xs[j >> 7][j & 127] = x[(size_t)n0 * IN_F + j];
    __syncthreads();

    float aq[P1_NB], ak[P1_NB], av[P1_NB], as_[P1_NB];
#pragma unroll
    for (int n = 0; n < P1_NB; n++) { aq[n] = ak[n] = av[n] = as_[n] = 0.f; }

    for (int i = 0; i < IN_F; i++) {
        float wq = Wq[i * HC + t];
        float wk = Wk[i * HC + t];
        float wv = Wv[i * HC + t];
        float ws = Ws[i * HC + t];
#pragma unroll
        for (int n = 0; n < P1_NB; n++) {
            float xv = xs[n][i];
            aq[n] += xv * wq; ak[n] += xv * wk;
            av[n] += xv * wv; as_[n] += xv * ws;
        }
    }
    float bqv = bq[t], bkv = bk[t], bvv = bv[t], bsv = bs[t];
#pragma unroll
    for (int n = 0; n < P1_NB; n++) {
        size_t o = (size_t)(n0 + n) * HC + t;
        q1[o] = aq[n] + bqv; k1[o] = ak[n] + bkv;
        v1[o] = av[n] + bvv; s1[o] = as_[n] + bsv;
    }
}

// ---------------------------------------------------------------- histogram of dst
__global__ __launch_bounds__(256) void hist_kernel(
    const int* __restrict__ ei, int* __restrict__ count)
{
    int e = blockIdx.x * 256 + threadIdx.x;
    if (e < N_EDGES) atomicAdd(count + ei[N_EDGES + e], 1);
}

// ---------------------------------------------------------------- exclusive scan (1 block)
__global__ __launch_bounds__(256) void scan_kernel(
    const int* __restrict__ count, int* __restrict__ offs, int* __restrict__ cursor)
{
    __shared__ int partial[256];
    const int t = threadIdx.x;
    const int CHUNK = (N_NODES + 255) / 256;
    int base = t * CHUNK;
    int lim  = base + CHUNK < N_NODES ? base + CHUNK : N_NODES;
    int s = 0;
    for (int i = base; i < lim; ++i) s += count[i];
    partial[t] = s;
    __syncthreads();
    for (int d = 1; d < 256; d <<= 1) {
        int u = (t >= d) ? partial[t - d] : 0;
        __syncthreads();
        partial[t] += u;
        __syncthreads();
    }
    int run = partial[t] - s;   // exclusive base of this chunk
    for (int i = base; i < lim; ++i) {
        offs[i] = run; cursor[i] = run;
        run += count[i];
    }
    if (t == 255) offs[N_NODES] = partial[255];
}

// ---------------------------------------------------------------- scatter edges to dst-sorted order
__global__ __launch_bounds__(256) void scatter_kernel(
    const int* __restrict__ ei, const float* __restrict__ ea,
    int* __restrict__ cursor,
    int* __restrict__ srcs, float2* __restrict__ eap)
{
    int e = blockIdx.x * 256 + threadIdx.x;
    if (e >= N_EDGES) return;
    int dst = ei[N_EDGES + e];
    int pos = atomicAdd(cursor + dst, 1);
    srcs[pos] = ei[e];
    eap[pos]  = make_float2(ea[(size_t)e * 2], ea[(size_t)e * 2 + 1]);
}

// ---------------------------------------------------------------- layer1 attention: one wave per dst node
// lane = channel (64), head = lane>>4. Online softmax per head, all in registers.
// Fuses logits + softmax + accumulate + skip + ELU.
__global__ __launch_bounds__(256) void attn1_kernel(
    const int* __restrict__ offs, const int* __restrict__ srcs,
    const float2* __restrict__ eap, const float* __restrict__ We,
    const float* __restrict__ q1, const float* __restrict__ k1,
    const float* __restrict__ v1, const float* __restrict__ s1,
    float* __restrict__ h)
{
    int n    = (blockIdx.x * 256 + threadIdx.x) >> 6;
    int lane = threadIdx.x & 63;
    if (n >= N_NODES) return;

    float qv  = q1[(size_t)n * HC + lane];
    float We0 = We[lane], We1 = We[HC + lane];
    int beg = offs[n], end = offs[n + 1];

    float m = -3.402823466e38f, l = 0.f, acc = 0.f;
    for (int i = beg; i < end; ++i) {
        int src = srcs[i];
        float2 eav = eap[i];
        float ec = eav.x * We0 + eav.y * We1;
        size_t sb = (size_t)src * HC + lane;
        float kk = k1[sb] + ec;
        float p = qv * kk;
        p += __shfl_xor(p, 1); p += __shfl_xor(p, 2);
        p += __shfl_xor(p, 4); p += __shfl_xor(p, 8);   // 16-lane head sum
        float logit = p * 0.25f;                        // 1/sqrt(16)
        float vv = v1[sb] + ec;
        float mn = fmaxf(m, logit);
        float sc = __expf(m - mn);
        float pe = __expf(logit - mn);
        l   = l   * sc + pe;
        acc = acc * sc + pe * vv;
        m = mn;
    }
    float att = (end > beg) ? acc / l : 0.f;
    float o = att + s1[(size_t)n * HC + lane];
    h[(size_t)n * HC + lane] = o > 0.f ? o : expm1f(o);   // ELU fused
}

// ---------------------------------------------------------------- layer2 node projections (64 -> 7, x4 matrices)
__global__ __launch_bounds__(256) void proj2_kernel(
    const float* __restrict__ h,
    const float* __restrict__ Wq, const float* __restrict__ bq,
    const float* __restrict__ Wk, const float* __restrict__ bk,
    const float* __restrict__ Wv, const float* __restrict__ bv,
    const float* __restrict__ Ws, const float* __restrict__ bs,
    float* __restrict__ q2, float* __restrict__ k2,
    float* __restrict__ v2, float* __restrict__ s2)
{
    __shared__ float hs[8][HC];
    const int t  = threadIdx.x;
    const int n0 = blockIdx.x * 8;
    for (int j = t; j < 8 * HC; j += 256) {
        size_t g = (size_t)n0 * HC + j;
        if (g < (size_t)N_NODES * HC) hs[j >> 6][j & 63] = h[g];
    }
    __syncthreads();

    int ni = t >> 5, j = t & 31;
    int n = n0 + ni;
    if (j < 28 && n < N_NODES) {
        int mtx = j / 7, c = j % 7;
        const float* W = (mtx == 0) ? Wq : (mtx == 1) ? Wk : (mtx == 2) ? Wv : Ws;
        const float* B = (mtx == 0) ? bq : (mtx == 1) ? bk : (mtx == 2) ? bv : bs;
        float acc = B[c];
        for (int i = 0; i < HC; i++)
            acc += hs[ni][i] * W[i * OUTF + c];
        float* dstp = (mtx == 0) ? q2 : (mtx == 1) ? k2 : (mtx == 2) ? v2 : s2;
        dstp[(size_t)n * OUTF + c] = acc;
    }
}

// ---------------------------------------------------------------- layer2 attention: one wave per dst node
// lanes parallel over edges, per-lane online softmax, wave merge; fuses final store.
__global__ __launch_bounds__(256) void attn2_kernel(
    const int* __restrict__ offs, const int* __restrict__ srcs,
    const float* __restrict__ q2, const float* __restrict__ k2,
    const float* __restrict__ v2, const float* __restrict__ s2,
    float* __restrict__ out)
{
    int n    = (blockIdx.x * 256 + threadIdx.x) >> 6;
    int lane = threadIdx.x & 63;
    if (n >= N_NODES) return;

    float q[OUTF];
#pragma unroll
    for (int c = 0; c < OUTF; c++) q[c] = q2[(size_t)n * OUTF + c];
    int beg = offs[n], end = offs[n + 1];

    float m = -3.402823466e38f, l = 0.f, a[OUTF];
#pragma unroll
    for (int c = 0; c < OUTF; c++) a[c] = 0.f;

    for (int i = beg + lane; i < end; i += 64) {
        int src = srcs[i];
        float dot = 0.f;
#pragma unroll
        for (int c = 0; c < OUTF; c++) dot += q[c] * k2[(size_t)src * OUTF + c];
        float logit = dot * 0.37796447300922725f;       // 1/sqrt(7)
        float mn = fmaxf(m, logit);
        float sc = __expf(m - mn);
        float pe = __expf(logit - mn);
        l = l * sc + pe;
#pragma unroll
        for (int c = 0; c < OUTF; c++) a[c] = a[c] * sc + pe * v2[(size_t)src * OUTF + c];
        m = mn;
    }

    if (end > beg) {
        float M = m;
        for (int d = 1; d < 64; d <<= 1) M = fmaxf(M, __shfl_xor(M, d));
        float sc = __expf(m - M);      // m at floor -> underflows to 0; l was 0 anyway
        l *= sc;
#pragma unroll
        for (int c = 0; c < OUTF; c++) a[c] *= sc;
        for (int d = 1; d < 64; d <<= 1) {
            l += __shfl_xor(l, d);
#pragma unroll
            for (int c = 0; c < OUTF; c++) a[c] += __shfl_xor(a[c], d);
        }
        if (lane == 0) {
            float inv = 1.f / fmaxf(l, 1e-16f);
#pragma unroll
            for (int c = 0; c < OUTF; c++)
                out[(size_t)n * OUTF + c] = a[c] * inv + s2[(size_t)n * OUTF + c];
        }
    } else if (lane == 0) {
#pragma unroll
        for (int c = 0; c < OUTF; c++)
            out[(size_t)n * OUTF + c] = s2[(size_t)n * OUTF + c];
    }
}

// ----------------------------------------------------------------
extern "C" void kernel_launch(void* const* d_in, const int* in_sizes, int n_in,
                              void* d_out, int out_size, void* d_ws, size_t ws_size,
                              hipStream_t stream)
{
    const float* x    = (const float*)d_in[0];
    const float* ea   = (const float*)d_in[1];
    const int*   ei   = (const int*)d_in[2];
    const float* Wq1  = (const float*)d_in[3];
    const float* bq1  = (const float*)d_in[4];
    const float* Wk1  = (const float*)d_in[5];
    const float* bk1  = (const float*)d_in[6];
    const float* Wv1  = (const float*)d_in[7];
    const float* bv1  = (const float*)d_in[8];
    const float* We1  = (const float*)d_in[9];
    const float* Ws1  = (const float*)d_in[10];
    const float* bs1  = (const float*)d_in[11];
    const float* Wq2  = (const float*)d_in[12];
    const float* bq2  = (const float*)d_in[13];
    const float* Wk2  = (const float*)d_in[14];
    const float* bk2  = (const float*)d_in[15];
    const float* Wv2  = (const float*)d_in[16];
    const float* bv2  = (const float*)d_in[17];
    const float* Ws2  = (const float*)d_in[18];
    const float* bs2  = (const float*)d_in[19];
    float* out = (float*)d_out;

    // workspace layout (f32 words), ~76 MB total
    float* ws = (float*)d_ws;
    float*  q1   = ws;                               // N*64
    float*  k1   = q1 + (size_t)N_NODES * HC;
    float*  v1   = k1 + (size_t)N_NODES * HC;
    float*  s1   = v1 + (size_t)N_NODES * HC;
    float*  hbuf = s1 + (size_t)N_NODES * HC;        // N*64
    float2* eap  = (float2*)(hbuf + (size_t)N_NODES * HC);  // E (8B aligned: even offset)
    float*  q2   = (float*)(eap + N_EDGES);          // N*7
    float*  k2   = q2 + (size_t)N_NODES * OUTF;
    float*  v2   = k2 + (size_t)N_NODES * OUTF;
    float*  s2   = v2 + (size_t)N_NODES * OUTF;
    int*    srcs   = (int*)(s2 + (size_t)N_NODES * OUTF);   // E
    int*    count  = srcs + N_EDGES;                 // N
    int*    offs   = count + N_NODES;                // N+1
    int*    cursor = offs + N_NODES + 1;             // N

    const int eb = (N_EDGES + 255) / 256;
    const int nwave_blocks = (N_NODES * 64 + 255) / 256;

    init_kernel<<<(N_NODES + 255) / 256, 256, 0, stream>>>(count);

    proj1_kernel<<<N_NODES / P1_NB, 64, 0, stream>>>(
        x, Wq1, bq1, Wk1, bk1, Wv1, bv1, Ws1, bs1, q1, k1, v1, s1);

    hist_kernel<<<eb, 256, 0, stream>>>(ei, count);
    scan_kernel<<<1, 256, 0, stream>>>(count, offs, cursor);
    scatter_kernel<<<eb, 256, 0, stream>>>(ei, ea, cursor, srcs, eap);

    attn1_kernel<<<nwave_blocks, 256, 0, stream>>>(
        offs, srcs, eap, We1, q1, k1, v1, s1, hbuf);

    proj2_kernel<<<(N_NODES + 7) / 8, 256, 0, stream>>>(
        hbuf, Wq2, bq2, Wk2, bk2, Wv2, bv2, Ws2, bs2, q2, k2, v2, s2);

    attn2_kernel<<<nwave_blocks, 256, 0, stream>>>(
        offs, srcs, q2, k2, v2, s2, out);
}

// Round 5
// 385.926 us; speedup vs baseline: 2.2990x; 1.2959x over previous
//
#include <hip/hip_runtime.h>

// TransformerClassification: 2-layer PyG TransformerConv GNN on MI355X.
// Round 5: parallelize the exclusive scan (was a 121us single-block serial
// kernel = 24% of runtime). 3-phase scan: block-scan -> scan block sums ->
// add offsets. Everything else unchanged from the passing round-4 kernel.

#define N_NODES 50000
#define N_EDGES 800000
#define IN_F    128
#define HC      64      // heads*ch layer1
#define NH      4
#define CH      16
#define OUTF    7

#define NSB ((N_NODES + 255) / 256)   // 196 scan blocks

// ---------------------------------------------------------------- init: zero the histogram
__global__ __launch_bounds__(256) void init_kernel(int* __restrict__ count)
{
    int i = blockIdx.x * 256 + threadIdx.x;
    if (i < N_NODES) count[i] = 0;
}

// ---------------------------------------------------------------- layer1 node projections
// 16 nodes per block, 64 threads (one per output column).
#define P1_NB 16
__global__ __launch_bounds__(64) void proj1_kernel(
    const float* __restrict__ x,
    const float* __restrict__ Wq, const float* __restrict__ bq,
    const float* __restrict__ Wk, const float* __restrict__ bk,
    const float* __restrict__ Wv, const float* __restrict__ bv,
    const float* __restrict__ Ws, const float* __restrict__ bs,
    float* __restrict__ q1, float* __restrict__ k1,
    float* __restrict__ v1, float* __restrict__ s1)
{
    __shared__ float xs[P1_NB][IN_F];
    const int t  = threadIdx.x;          // 0..63 = output column
    const int n0 = blockIdx.x * P1_NB;

    for (int j = t; j < P1_NB * IN_F; j += 64)
        xs[j >> 7][j & 127] = x[(size_t)n0 * IN_F + j];
    __syncthreads();

    float aq[P1_NB], ak[P1_NB], av[P1_NB], as_[P1_NB];
#pragma unroll
    for (int n = 0; n < P1_NB; n++) { aq[n] = ak[n] = av[n] = as_[n] = 0.f; }

    for (int i = 0; i < IN_F; i++) {
        float wq = Wq[i * HC + t];
        float wk = Wk[i * HC + t];
        float wv = Wv[i * HC + t];
        float ws = Ws[i * HC + t];
#pragma unroll
        for (int n = 0; n < P1_NB; n++) {
            float xv = xs[n][i];
            aq[n] += xv * wq; ak[n] += xv * wk;
            av[n] += xv * wv; as_[n] += xv * ws;
        }
    }
    float bqv = bq[t], bkv = bk[t], bvv = bv[t], bsv = bs[t];
#pragma unroll
    for (int n = 0; n < P1_NB; n++) {
        size_t o = (size_t)(n0 + n) * HC + t;
        q1[o] = aq[n] + bqv; k1[o] = ak[n] + bkv;
        v1[o] = av[n] + bvv; s1[o] = as_[n] + bsv;
    }
}

// ---------------------------------------------------------------- histogram of dst
__global__ __launch_bounds__(256) void hist_kernel(
    const int* __restrict__ ei, int* __restrict__ count)
{
    int e = blockIdx.x * 256 + threadIdx.x;
    if (e < N_EDGES) atomicAdd(count + ei[N_EDGES + e], 1);
}

// ---------------------------------------------------------------- scan phase 1: block-local exclusive scan
__global__ __launch_bounds__(256) void scan1_kernel(
    const int* __restrict__ count, int* __restrict__ pre, int* __restrict__ bsum)
{
    __shared__ int sdata[256];
    const int t = threadIdx.x;
    const int i = blockIdx.x * 256 + t;
    int v = (i < N_NODES) ? count[i] : 0;
    sdata[t] = v;
    __syncthreads();
    for (int d = 1; d < 256; d <<= 1) {
        int u = (t >= d) ? sdata[t - d] : 0;
        __syncthreads();
        sdata[t] += u;
        __syncthreads();
    }
    if (i < N_NODES) pre[i] = sdata[t] - v;      // exclusive within block
    if (t == 255) bsum[blockIdx.x] = sdata[255]; // block total
}

// ---------------------------------------------------------------- scan phase 2: scan the 196 block sums (1 block)
__global__ __launch_bounds__(256) void scan2_kernel(
    int* __restrict__ bsum, int* __restrict__ bofs)
{
    __shared__ int sdata[256];
    const int t = threadIdx.x;
    int v = (t < NSB) ? bsum[t] : 0;
    sdata[t] = v;
    __syncthreads();
    for (int d = 1; d < 256; d <<= 1) {
        int u = (t >= d) ? sdata[t - d] : 0;
        __syncthreads();
        sdata[t] += u;
        __syncthreads();
    }
    if (t < NSB) bofs[t] = sdata[t] - v;         // exclusive block offset
}

// ---------------------------------------------------------------- scan phase 3: add block offset, write offs+cursor
__global__ __launch_bounds__(256) void scan3_kernel(
    const int* __restrict__ pre, const int* __restrict__ bofs,
    int* __restrict__ offs, int* __restrict__ cursor)
{
    const int i = blockIdx.x * 256 + threadIdx.x;
    if (i < N_NODES) {
        int o = pre[i] + bofs[i >> 8];
        offs[i] = o; cursor[i] = o;
    }
    if (i == 0) offs[N_NODES] = N_EDGES;
}

// ---------------------------------------------------------------- scatter edges to dst-sorted order
__global__ __launch_bounds__(256) void scatter_kernel(
    const int* __restrict__ ei, const float* __restrict__ ea,
    int* __restrict__ cursor,
    int* __restrict__ srcs, float2* __restrict__ eap)
{
    int e = blockIdx.x * 256 + threadIdx.x;
    if (e >= N_EDGES) return;
    int dst = ei[N_EDGES + e];
    int pos = atomicAdd(cursor + dst, 1);
    srcs[pos] = ei[e];
    eap[pos]  = make_float2(ea[(size_t)e * 2], ea[(size_t)e * 2 + 1]);
}

// ---------------------------------------------------------------- layer1 attention: one wave per dst node
// lane = channel (64), head = lane>>4. Online softmax per head, all in registers.
// Fuses logits + softmax + accumulate + skip + ELU.
__global__ __launch_bounds__(256) void attn1_kernel(
    const int* __restrict__ offs, const int* __restrict__ srcs,
    const float2* __restrict__ eap, const float* __restrict__ We,
    const float* __restrict__ q1, const float* __restrict__ k1,
    const float* __restrict__ v1, const float* __restrict__ s1,
    float* __restrict__ h)
{
    int n    = (blockIdx.x * 256 + threadIdx.x) >> 6;
    int lane = threadIdx.x & 63;
    if (n >= N_NODES) return;

    float qv  = q1[(size_t)n * HC + lane];
    float We0 = We[lane], We1 = We[HC + lane];
    int beg = offs[n], end = offs[n + 1];

    float m = -3.402823466e38f, l = 0.f, acc = 0.f;
    for (int i = beg; i < end; ++i) {
        int src = srcs[i];
        float2 eav = eap[i];
        float ec = eav.x * We0 + eav.y * We1;
        size_t sb = (size_t)src * HC + lane;
        float kk = k1[sb] + ec;
        float p = qv * kk;
        p += __shfl_xor(p, 1); p += __shfl_xor(p, 2);
        p += __shfl_xor(p, 4); p += __shfl_xor(p, 8);   // 16-lane head sum
        float logit = p * 0.25f;                        // 1/sqrt(16)
        float vv = v1[sb] + ec;
        float mn = fmaxf(m, logit);
        float sc = __expf(m - mn);
        float pe = __expf(logit - mn);
        l   = l   * sc + pe;
        acc = acc * sc + pe * vv;
        m = mn;
    }
    float att = (end > beg) ? acc / l : 0.f;
    float o = att + s1[(size_t)n * HC + lane];
    h[(size_t)n * HC + lane] = o > 0.f ? o : expm1f(o);   // ELU fused
}

// ---------------------------------------------------------------- layer2 node projections (64 -> 7, x4 matrices)
__global__ __launch_bounds__(256) void proj2_kernel(
    const float* __restrict__ h,
    const float* __restrict__ Wq, const float* __restrict__ bq,
    const float* __restrict__ Wk, const float* __restrict__ bk,
    const float* __restrict__ Wv, const float* __restrict__ bv,
    const float* __restrict__ Ws, const float* __restrict__ bs,
    float* __restrict__ q2, float* __restrict__ k2,
    float* __restrict__ v2, float* __restrict__ s2)
{
    __shared__ float hs[8][HC];
    const int t  = threadIdx.x;
    const int n0 = blockIdx.x * 8;
    for (int j = t; j < 8 * HC; j += 256) {
        size_t g = (size_t)n0 * HC + j;
        if (g < (size_t)N_NODES * HC) hs[j >> 6][j & 63] = h[g];
    }
    __syncthreads();

    int ni = t >> 5, j = t & 31;
    int n = n0 + ni;
    if (j < 28 && n < N_NODES) {
        int mtx = j / 7, c = j % 7;
        const float* W = (mtx == 0) ? Wq : (mtx == 1) ? Wk : (mtx == 2) ? Wv : Ws;
        const float* B = (mtx == 0) ? bq : (mtx == 1) ? bk : (mtx == 2) ? bv : bs;
        float acc = B[c];
        for (int i = 0; i < HC; i++)
            acc += hs[ni][i] * W[i * OUTF + c];
        float* dstp = (mtx == 0) ? q2 : (mtx == 1) ? k2 : (mtx == 2) ? v2 : s2;
        dstp[(size_t)n * OUTF + c] = acc;
    }
}

// ---------------------------------------------------------------- layer2 attention: one wave per dst node
// lanes parallel over edges, per-lane online softmax, wave merge; fuses final store.
__global__ __launch_bounds__(256) void attn2_kernel(
    const int* __restrict__ offs, const int* __restrict__ srcs,
    const float* __restrict__ q2, const float* __restrict__ k2,
    const float* __restrict__ v2, const float* __restrict__ s2,
    float* __restrict__ out)
{
    int n    = (blockIdx.x * 256 + threadIdx.x) >> 6;
    int lane = threadIdx.x & 63;
    if (n >= N_NODES) return;

    float q[OUTF];
#pragma unroll
    for (int c = 0; c < OUTF; c++) q[c] = q2[(size_t)n * OUTF + c];
    int beg = offs[n], end = offs[n + 1];

    float m = -3.402823466e38f, l = 0.f, a[OUTF];
#pragma unroll
    for (int c = 0; c < OUTF; c++) a[c] = 0.f;

    for (int i = beg + lane; i < end; i += 64) {
        int src = srcs[i];
        float dot = 0.f;
#pragma unroll
        for (int c = 0; c < OUTF; c++) dot += q[c] * k2[(size_t)src * OUTF + c];
        float logit = dot * 0.37796447300922725f;       // 1/sqrt(7)
        float mn = fmaxf(m, logit);
        float sc = __expf(m - mn);
        float pe = __expf(logit - mn);
        l = l * sc + pe;
#pragma unroll
        for (int c = 0; c < OUTF; c++) a[c] = a[c] * sc + pe * v2[(size_t)src * OUTF + c];
        m = mn;
    }

    if (end > beg) {
        float M = m;
        for (int d = 1; d < 64; d <<= 1) M = fmaxf(M, __shfl_xor(M, d));
        float sc = __expf(m - M);      // m at floor -> underflows to 0; l was 0 anyway
        l *= sc;
#pragma unroll
        for (int c = 0; c < OUTF; c++) a[c] *= sc;
        for (int d = 1; d < 64; d <<= 1) {
            l += __shfl_xor(l, d);
#pragma unroll
            for (int c = 0; c < OUTF; c++) a[c] += __shfl_xor(a[c], d);
        }
        if (lane == 0) {
            float inv = 1.f / fmaxf(l, 1e-16f);
#pragma unroll
            for (int c = 0; c < OUTF; c++)
                out[(size_t)n * OUTF + c] = a[c] * inv + s2[(size_t)n * OUTF + c];
        }
    } else if (lane == 0) {
#pragma unroll
        for (int c = 0; c < OUTF; c++)
            out[(size_t)n * OUTF + c] = s2[(size_t)n * OUTF + c];
    }
}

// ----------------------------------------------------------------
extern "C" void kernel_launch(void* const* d_in, const int* in_sizes, int n_in,
                              void* d_out, int out_size, void* d_ws, size_t ws_size,
                              hipStream_t stream)
{
    const float* x    = (const float*)d_in[0];
    const float* ea   = (const float*)d_in[1];
    const int*   ei   = (const int*)d_in[2];
    const float* Wq1  = (const float*)d_in[3];
    const float* bq1  = (const float*)d_in[4];
    const float* Wk1  = (const float*)d_in[5];
    const float* bk1  = (const float*)d_in[6];
    const float* Wv1  = (const float*)d_in[7];
    const float* bv1  = (const float*)d_in[8];
    const float* We1  = (const float*)d_in[9];
    const float* Ws1  = (const float*)d_in[10];
    const float* bs1  = (const float*)d_in[11];
    const float* Wq2  = (const float*)d_in[12];
    const float* bq2  = (const float*)d_in[13];
    const float* Wk2  = (const float*)d_in[14];
    const float* bk2  = (const float*)d_in[15];
    const float* Wv2  = (const float*)d_in[16];
    const float* bv2  = (const float*)d_in[17];
    const float* Ws2  = (const float*)d_in[18];
    const float* bs2  = (const float*)d_in[19];
    float* out = (float*)d_out;

    // workspace layout (f32 words), ~76 MB total
    float* ws = (float*)d_ws;
    float*  q1   = ws;                               // N*64
    float*  k1   = q1 + (size_t)N_NODES * HC;
    float*  v1   = k1 + (size_t)N_NODES * HC;
    float*  s1   = v1 + (size_t)N_NODES * HC;
    float*  hbuf = s1 + (size_t)N_NODES * HC;        // N*64
    float2* eap  = (float2*)(hbuf + (size_t)N_NODES * HC);  // E (8B aligned: even offset)
    float*  q2   = (float*)(eap + N_EDGES);          // N*7
    float*  k2   = q2 + (size_t)N_NODES * OUTF;
    float*  v2   = k2 + (size_t)N_NODES * OUTF;
    float*  s2   = v2 + (size_t)N_NODES * OUTF;
    int*    srcs   = (int*)(s2 + (size_t)N_NODES * OUTF);   // E
    int*    count  = srcs + N_EDGES;                 // N
    int*    offs   = count + N_NODES;                // N+1
    int*    cursor = offs + N_NODES + 1;             // N
    int*    pre    = cursor + N_NODES;               // N
    int*    bsum   = pre + N_NODES;                  // NSB
    int*    bofs   = bsum + NSB;                     // NSB

    const int eb = (N_EDGES + 255) / 256;
    const int nwave_blocks = (N_NODES * 64 + 255) / 256;

    init_kernel<<<(N_NODES + 255) / 256, 256, 0, stream>>>(count);

    proj1_kernel<<<N_NODES / P1_NB, 64, 0, stream>>>(
        x, Wq1, bq1, Wk1, bk1, Wv1, bv1, Ws1, bs1, q1, k1, v1, s1);

    hist_kernel<<<eb, 256, 0, stream>>>(ei, count);
    scan1_kernel<<<NSB, 256, 0, stream>>>(count, pre, bsum);
    scan2_kernel<<<1, 256, 0, stream>>>(bsum, bofs);
    scan3_kernel<<<NSB, 256, 0, stream>>>(pre, bofs, offs, cursor);
    scatter_kernel<<<eb, 256, 0, stream>>>(ei, ea, cursor, srcs, eap);

    attn1_kernel<<<nwave_blocks, 256, 0, stream>>>(
        offs, srcs, eap, We1, q1, k1, v1, s1, hbuf);

    proj2_kernel<<<(N_NODES + 7) / 8, 256, 0, stream>>>(
        hbuf, Wq2, bq2, Wk2, bk2, Wv2, bv2, Ws2, bs2, q2, k2, v2, s2);

    attn2_kernel<<<nwave_blocks, 256, 0, stream>>>(
        offs, srcs, q2, k2, v2, s2, out);
}

// Round 6
// 332.432 us; speedup vs baseline: 2.6689x; 1.1609x over previous
//
#include <hip/hip_runtime.h>

// TransformerClassification: 2-layer PyG TransformerConv GNN on MI355X.
// Round 6: attn1 latency-chain fix (DPP 16-lane reduce instead of ds_bpermute
// shfl; unroll-2 online softmax), packed 16B edge records (halve scatter
// write sectors), attn2 padded/interleaved kv rows + DPP-accelerated merge.

#define N_NODES 50000
#define N_EDGES 800000
#define IN_F    128
#define HC      64      // heads*ch layer1
#define NH      4
#define CH      16
#define OUTF    7

#define NSB ((N_NODES + 255) / 256)   // 196 scan blocks

// ---------------- DPP helpers: butterfly reduce within each 16-lane row ----
// quad_perm(1,0,3,2)=0xB1 (xor1), quad_perm(2,3,0,1)=0x4E (xor2),
// row_ror:4=0x124, row_ror:8=0x128. After the 4 steps every lane of the
// 16-lane row holds the row total (sum) / row max.
__device__ __forceinline__ float dpp_add16(float x) {
    int t;
    t = __builtin_amdgcn_update_dpp(0, __float_as_int(x), 0xB1, 0xF, 0xF, false);
    x += __int_as_float(t);
    t = __builtin_amdgcn_update_dpp(0, __float_as_int(x), 0x4E, 0xF, 0xF, false);
    x += __int_as_float(t);
    t = __builtin_amdgcn_update_dpp(0, __float_as_int(x), 0x124, 0xF, 0xF, false);
    x += __int_as_float(t);
    t = __builtin_amdgcn_update_dpp(0, __float_as_int(x), 0x128, 0xF, 0xF, false);
    x += __int_as_float(t);
    return x;
}
__device__ __forceinline__ float dpp_max16(float x) {
    int t;
    t = __builtin_amdgcn_update_dpp(0, __float_as_int(x), 0xB1, 0xF, 0xF, false);
    x = fmaxf(x, __int_as_float(t));
    t = __builtin_amdgcn_update_dpp(0, __float_as_int(x), 0x4E, 0xF, 0xF, false);
    x = fmaxf(x, __int_as_float(t));
    t = __builtin_amdgcn_update_dpp(0, __float_as_int(x), 0x124, 0xF, 0xF, false);
    x = fmaxf(x, __int_as_float(t));
    t = __builtin_amdgcn_update_dpp(0, __float_as_int(x), 0x128, 0xF, 0xF, false);
    x = fmaxf(x, __int_as_float(t));
    return x;
}

// ---------------------------------------------------------------- init: zero the histogram
__global__ __launch_bounds__(256) void init_kernel(int* __restrict__ count)
{
    int i = blockIdx.x * 256 + threadIdx.x;
    if (i < N_NODES) count[i] = 0;
}

// ---------------------------------------------------------------- layer1 node projections
#define P1_NB 16
__global__ __launch_bounds__(64) void proj1_kernel(
    const float* __restrict__ x,
    const float* __restrict__ Wq, const float* __restrict__ bq,
    const float* __restrict__ Wk, const float* __restrict__ bk,
    const float* __restrict__ Wv, const float* __restrict__ bv,
    const float* __restrict__ Ws, const float* __restrict__ bs,
    float* __restrict__ q1, float* __restrict__ k1,
    float* __restrict__ v1, float* __restrict__ s1)
{
    __shared__ float xs[P1_NB][IN_F];
    const int t  = threadIdx.x;          // 0..63 = output column
    const int n0 = blockIdx.x * P1_NB;

    for (int j = t; j < P1_NB * IN_F; j += 64)
        xs[j >> 7][j & 127] = x[(size_t)n0 * IN_F + j];
    __syncthreads();

    float aq[P1_NB], ak[P1_NB], av[P1_NB], as_[P1_NB];
#pragma unroll
    for (int n = 0; n < P1_NB; n++) { aq[n] = ak[n] = av[n] = as_[n] = 0.f; }

    for (int i = 0; i < IN_F; i++) {
        float wq = Wq[i * HC + t];
        float wk = Wk[i * HC + t];
        float wv = Wv[i * HC + t];
        float ws = Ws[i * HC + t];
#pragma unroll
        for (int n = 0; n < P1_NB; n++) {
            float xv = xs[n][i];
            aq[n] += xv * wq; ak[n] += xv * wk;
            av[n] += xv * wv; as_[n] += xv * ws;
        }
    }
    float bqv = bq[t], bkv = bk[t], bvv = bv[t], bsv = bs[t];
#pragma unroll
    for (int n = 0; n < P1_NB; n++) {
        size_t o = (size_t)(n0 + n) * HC + t;
        q1[o] = aq[n] + bqv; k1[o] = ak[n] + bkv;
        v1[o] = av[n] + bvv; s1[o] = as_[n] + bsv;
    }
}

// ---------------------------------------------------------------- histogram of dst
__global__ __launch_bounds__(256) void hist_kernel(
    const int* __restrict__ ei, int* __restrict__ count)
{
    int e = blockIdx.x * 256 + threadIdx.x;
    if (e < N_EDGES) atomicAdd(count + ei[N_EDGES + e], 1);
}

// ---------------------------------------------------------------- scan phase 1
__global__ __launch_bounds__(256) void scan1_kernel(
    const int* __restrict__ count, int* __restrict__ pre, int* __restrict__ bsum)
{
    __shared__ int sdata[256];
    const int t = threadIdx.x;
    const int i = blockIdx.x * 256 + t;
    int v = (i < N_NODES) ? count[i] : 0;
    sdata[t] = v;
    __syncthreads();
    for (int d = 1; d < 256; d <<= 1) {
        int u = (t >= d) ? sdata[t - d] : 0;
        __syncthreads();
        sdata[t] += u;
        __syncthreads();
    }
    if (i < N_NODES) pre[i] = sdata[t] - v;
    if (t == 255) bsum[blockIdx.x] = sdata[255];
}

// ---------------------------------------------------------------- scan phase 2 (1 block)
__global__ __launch_bounds__(256) void scan2_kernel(
    int* __restrict__ bsum, int* __restrict__ bofs)
{
    __shared__ int sdata[256];
    const int t = threadIdx.x;
    int v = (t < NSB) ? bsum[t] : 0;
    sdata[t] = v;
    __syncthreads();
    for (int d = 1; d < 256; d <<= 1) {
        int u = (t >= d) ? sdata[t - d] : 0;
        __syncthreads();
        sdata[t] += u;
        __syncthreads();
    }
    if (t < NSB) bofs[t] = sdata[t] - v;
}

// ---------------------------------------------------------------- scan phase 3
__global__ __launch_bounds__(256) void scan3_kernel(
    const int* __restrict__ pre, const int* __restrict__ bofs,
    int* __restrict__ offs, int* __restrict__ cursor)
{
    const int i = blockIdx.x * 256 + threadIdx.x;
    if (i < N_NODES) {
        int o = pre[i] + bofs[i >> 8];
        offs[i] = o; cursor[i] = o;
    }
    if (i == 0) offs[N_NODES] = N_EDGES;
}

// ---------------------------------------------------------------- scatter: one packed 16B record per edge
__global__ __launch_bounds__(256) void scatter_kernel(
    const int* __restrict__ ei, const float* __restrict__ ea,
    int* __restrict__ cursor, float4* __restrict__ erec)
{
    int e = blockIdx.x * 256 + threadIdx.x;
    if (e >= N_EDGES) return;
    int dst = ei[N_EDGES + e];
    int pos = atomicAdd(cursor + dst, 1);
    float4 r;
    r.x = __int_as_float(ei[e]);
    r.y = ea[(size_t)e * 2];
    r.z = ea[(size_t)e * 2 + 1];
    r.w = 0.f;
    erec[pos] = r;
}

// ---------------------------------------------------------------- layer1 attention: one wave per dst node
// lane = channel (64), head = lane>>4 (heads align with 16-lane DPP rows).
// Online softmax, unroll-2, DPP head-sum. Fuses skip + ELU.
__global__ __launch_bounds__(256) void attn1_kernel(
    const int* __restrict__ offs, const float4* __restrict__ erec,
    const float* __restrict__ We,
    const float* __restrict__ q1, const float* __restrict__ k1,
    const float* __restrict__ v1, const float* __restrict__ s1,
    float* __restrict__ h)
{
    int n    = (blockIdx.x * 256 + threadIdx.x) >> 6;
    int lane = threadIdx.x & 63;
    if (n >= N_NODES) return;

    float qv  = q1[(size_t)n * HC + lane];
    float We0 = We[lane], We1 = We[HC + lane];
    int beg = offs[n], end = offs[n + 1];

    float m = -3.402823466e38f, l = 0.f, acc = 0.f;
    int i = beg;
    for (; i + 1 < end; i += 2) {
        float4 r0 = erec[i], r1 = erec[i + 1];
        int s0 = __float_as_int(r0.x), s1v = __float_as_int(r1.x);
        float ec0 = r0.y * We0 + r0.z * We1;
        float ec1 = r1.y * We0 + r1.z * We1;
        size_t b0 = (size_t)s0 * HC + lane, b1 = (size_t)s1v * HC + lane;
        float k0 = k1[b0] + ec0, k1v = k1[b1] + ec1;
        float v0 = v1[b0] + ec0, v1r = v1[b1] + ec1;
        float p0 = dpp_add16(qv * k0) * 0.25f;       // 1/sqrt(16)
        float p1 = dpp_add16(qv * k1v) * 0.25f;
        float mn = fmaxf(m, fmaxf(p0, p1));
        float sm = __expf(m - mn);
        float e0 = __expf(p0 - mn);
        float e1 = __expf(p1 - mn);
        l   = l   * sm + e0 + e1;
        acc = acc * sm + e0 * v0 + e1 * v1r;
        m = mn;
    }
    if (i < end) {
        float4 r0 = erec[i];
        int s0 = __float_as_int(r0.x);
        float ec0 = r0.y * We0 + r0.z * We1;
        size_t b0 = (size_t)s0 * HC + lane;
        float k0 = k1[b0] + ec0;
        float v0 = v1[b0] + ec0;
        float p0 = dpp_add16(qv * k0) * 0.25f;
        float mn = fmaxf(m, p0);
        float sm = __expf(m - mn);
        float e0 = __expf(p0 - mn);
        l   = l   * sm + e0;
        acc = acc * sm + e0 * v0;
        m = mn;
    }
    float att = (end > beg) ? acc / l : 0.f;
    float o = att + s1[(size_t)n * HC + lane];
    h[(size_t)n * HC + lane] = o > 0.f ? o : expm1f(o);   // ELU fused
}

// ---------------------------------------------------------------- layer2 node projections (64 -> 7, x4)
// outputs: q2p/s2p padded to 8 floats; kv2 interleaved row of 16 floats
// (k at [0..6], v at [8..14]) -> one 64B sector per edge gather.
__global__ __launch_bounds__(256) void proj2_kernel(
    const float* __restrict__ h,
    const float* __restrict__ Wq, const float* __restrict__ bq,
    const float* __restrict__ Wk, const float* __restrict__ bk,
    const float* __restrict__ Wv, const float* __restrict__ bv,
    const float* __restrict__ Ws, const float* __restrict__ bs,
    float* __restrict__ q2p, float* __restrict__ kv2, float* __restrict__ s2p)
{
    __shared__ float hs[8][HC];
    const int t  = threadIdx.x;
    const int n0 = blockIdx.x * 8;
    for (int j = t; j < 8 * HC; j += 256) {
        size_t g = (size_t)n0 * HC + j;
        if (g < (size_t)N_NODES * HC) hs[j >> 6][j & 63] = h[g];
    }
    __syncthreads();

    int ni = t >> 5, j = t & 31;
    int n = n0 + ni;
    if (j < 28 && n < N_NODES) {
        int mtx = j / 7, c = j % 7;
        const float* W = (mtx == 0) ? Wq : (mtx == 1) ? Wk : (mtx == 2) ? Wv : Ws;
        const float* B = (mtx == 0) ? bq : (mtx == 1) ? bk : (mtx == 2) ? bv : bs;
        float acc = B[c];
        for (int i = 0; i < HC; i++)
            acc += hs[ni][i] * W[i * OUTF + c];
        if      (mtx == 0) q2p[(size_t)n * 8 + c]      = acc;
        else if (mtx == 1) kv2[(size_t)n * 16 + c]     = acc;
        else if (mtx == 2) kv2[(size_t)n * 16 + 8 + c] = acc;
        else               s2p[(size_t)n * 8 + c]      = acc;
    }
}

// ---------------------------------------------------------------- layer2 attention: one wave per dst node
// lanes parallel over edges; DPP-accelerated 64-lane merge; fuses final store.
__global__ __launch_bounds__(256) void attn2_kernel(
    const int* __restrict__ offs, const float4* __restrict__ erec,
    const float* __restrict__ q2p, const float* __restrict__ kv2,
    const float* __restrict__ s2p, float* __restrict__ out)
{
    int n    = (blockIdx.x * 256 + threadIdx.x) >> 6;
    int lane = threadIdx.x & 63;
    if (n >= N_NODES) return;

    float4 qa = *(const float4*)(q2p + (size_t)n * 8);
    float4 qb = *(const float4*)(q2p + (size_t)n * 8 + 4);
    int beg = offs[n], end = offs[n + 1];

    float m = -3.402823466e38f, l = 0.f, a[OUTF];
#pragma unroll
    for (int c = 0; c < OUTF; c++) a[c] = 0.f;

    for (int i = beg + lane; i < end; i += 64) {
        int src = __float_as_int(erec[i].x);
        const float4* kvp = (const float4*)(kv2 + (size_t)src * 16);
        float4 ka = kvp[0], kb = kvp[1], va = kvp[2], vb = kvp[3];
        float dot = qa.x * ka.x + qa.y * ka.y + qa.z * ka.z + qa.w * ka.w
                  + qb.x * kb.x + qb.y * kb.y + qb.z * kb.z;
        float logit = dot * 0.37796447300922725f;       // 1/sqrt(7)
        float mn = fmaxf(m, logit);
        float sc = __expf(m - mn);
        float pe = __expf(logit - mn);
        l = l * sc + pe;
        a[0] = a[0] * sc + pe * va.x;
        a[1] = a[1] * sc + pe * va.y;
        a[2] = a[2] * sc + pe * va.z;
        a[3] = a[3] * sc + pe * va.w;
        a[4] = a[4] * sc + pe * vb.x;
        a[5] = a[5] * sc + pe * vb.y;
        a[6] = a[6] * sc + pe * vb.z;
        m = mn;
    }

    if (end > beg) {
        // global max: DPP within rows, shfl across rows
        float M = dpp_max16(m);
        M = fmaxf(M, __shfl_xor(M, 16));
        M = fmaxf(M, __shfl_xor(M, 32));
        float sc = __expf(m - M);      // m at -FLT_MAX underflows to 0; l was 0 anyway
        l *= sc;
#pragma unroll
        for (int c = 0; c < OUTF; c++) a[c] *= sc;
        l = dpp_add16(l); l += __shfl_xor(l, 16); l += __shfl_xor(l, 32);
#pragma unroll
        for (int c = 0; c < OUTF; c++) {
            float t = dpp_add16(a[c]);
            t += __shfl_xor(t, 16); t += __shfl_xor(t, 32);
            a[c] = t;
        }
        if (lane == 0) {
            float inv = 1.f / fmaxf(l, 1e-16f);
#pragma unroll
            for (int c = 0; c < OUTF; c++)
                out[(size_t)n * OUTF + c] = a[c] * inv + s2p[(size_t)n * 8 + c];
        }
    } else if (lane == 0) {
#pragma unroll
        for (int c = 0; c < OUTF; c++)
            out[(size_t)n * OUTF + c] = s2p[(size_t)n * 8 + c];
    }
}

// ----------------------------------------------------------------
extern "C" void kernel_launch(void* const* d_in, const int* in_sizes, int n_in,
                              void* d_out, int out_size, void* d_ws, size_t ws_size,
                              hipStream_t stream)
{
    const float* x    = (const float*)d_in[0];
    const float* ea   = (const float*)d_in[1];
    const int*   ei   = (const int*)d_in[2];
    const float* Wq1  = (const float*)d_in[3];
    const float* bq1  = (const float*)d_in[4];
    const float* Wk1  = (const float*)d_in[5];
    const float* bk1  = (const float*)d_in[6];
    const float* Wv1  = (const float*)d_in[7];
    const float* bv1  = (const float*)d_in[8];
    const float* We1  = (const float*)d_in[9];
    const float* Ws1  = (const float*)d_in[10];
    const float* bs1  = (const float*)d_in[11];
    const float* Wq2  = (const float*)d_in[12];
    const float* bq2  = (const float*)d_in[13];
    const float* Wk2  = (const float*)d_in[14];
    const float* bk2  = (const float*)d_in[15];
    const float* Wv2  = (const float*)d_in[16];
    const float* bv2  = (const float*)d_in[17];
    const float* Ws2  = (const float*)d_in[18];
    const float* bs2  = (const float*)d_in[19];
    float* out = (float*)d_out;

    // workspace layout (f32 words), ~84 MB total; all segments 16B-aligned.
    float* ws = (float*)d_ws;
    float*  q1   = ws;                               // N*64
    float*  k1   = q1 + (size_t)N_NODES * HC;
    float*  v1   = k1 + (size_t)N_NODES * HC;
    float*  s1   = v1 + (size_t)N_NODES * HC;
    float*  hbuf = q1;                               // alias: attn1 reads q1[slot] then writes h[slot]
    float4* erec = (float4*)(s1 + (size_t)N_NODES * HC);    // E x 16B
    float*  q2p  = (float*)(erec + N_EDGES);         // N*8
    float*  kv2  = q2p + (size_t)N_NODES * 8;        // N*16
    float*  s2p  = kv2 + (size_t)N_NODES * 16;       // N*8
    int*    count  = (int*)(s2p + (size_t)N_NODES * 8);     // N
    int*    offs   = count + N_NODES;                // N+1
    int*    cursor = offs + N_NODES + 1;             // N
    int*    pre    = cursor + N_NODES;               // N
    int*    bsum   = pre + N_NODES;                  // NSB
    int*    bofs   = bsum + NSB;                     // NSB

    const int eb = (N_EDGES + 255) / 256;
    const int nwave_blocks = (N_NODES * 64 + 255) / 256;

    init_kernel<<<(N_NODES + 255) / 256, 256, 0, stream>>>(count);

    proj1_kernel<<<N_NODES / P1_NB, 64, 0, stream>>>(
        x, Wq1, bq1, Wk1, bk1, Wv1, bv1, Ws1, bs1, q1, k1, v1, s1);

    hist_kernel<<<eb, 256, 0, stream>>>(ei, count);
    scan1_kernel<<<NSB, 256, 0, stream>>>(count, pre, bsum);
    scan2_kernel<<<1, 256, 0, stream>>>(bsum, bofs);
    scan3_kernel<<<NSB, 256, 0, stream>>>(pre, bofs, offs, cursor);
    scatter_kernel<<<eb, 256, 0, stream>>>(ei, ea, cursor, erec);

    attn1_kernel<<<nwave_blocks, 256, 0, stream>>>(
        offs, erec, We1, q1, k1, v1, s1, hbuf);

    proj2_kernel<<<(N_NODES + 7) / 8, 256, 0, stream>>>(
        hbuf, Wq2, bq2, Wk2, bk2, Wv2, bv2, Ws2, bs2, q2p, kv2, s2p);

    attn2_kernel<<<nwave_blocks, 256, 0, stream>>>(
        offs, erec, q2p, kv2, s2p, out);
}

// Round 7
// 276.172 us; speedup vs baseline: 3.2126x; 1.2037x over previous
//
#include <hip/hip_runtime.h>

// TransformerClassification: 2-layer PyG TransformerConv GNN on MI355X.
// Round 7: rewrite proj2 (was 78us = 23%, latency-bound 64-deep serial chain
// with divergent global W loads). New: thread-per-node, W staged in LDS as
// [64][4][8] float4-readable rows, 32 VGPR accumulators, 2048 ILP-rich FMAs.

#define N_NODES 50000
#define N_EDGES 800000
#define IN_F    128
#define HC      64      // heads*ch layer1
#define NH      4
#define CH      16
#define OUTF    7

#define NSB ((N_NODES + 255) / 256)   // 196 scan blocks

// ---------------- DPP helpers: butterfly reduce within each 16-lane row ----
__device__ __forceinline__ float dpp_add16(float x) {
    int t;
    t = __builtin_amdgcn_update_dpp(0, __float_as_int(x), 0xB1, 0xF, 0xF, false);
    x += __int_as_float(t);
    t = __builtin_amdgcn_update_dpp(0, __float_as_int(x), 0x4E, 0xF, 0xF, false);
    x += __int_as_float(t);
    t = __builtin_amdgcn_update_dpp(0, __float_as_int(x), 0x124, 0xF, 0xF, false);
    x += __int_as_float(t);
    t = __builtin_amdgcn_update_dpp(0, __float_as_int(x), 0x128, 0xF, 0xF, false);
    x += __int_as_float(t);
    return x;
}
__device__ __forceinline__ float dpp_max16(float x) {
    int t;
    t = __builtin_amdgcn_update_dpp(0, __float_as_int(x), 0xB1, 0xF, 0xF, false);
    x = fmaxf(x, __int_as_float(t));
    t = __builtin_amdgcn_update_dpp(0, __float_as_int(x), 0x4E, 0xF, 0xF, false);
    x = fmaxf(x, __int_as_float(t));
    t = __builtin_amdgcn_update_dpp(0, __float_as_int(x), 0x124, 0xF, 0xF, false);
    x = fmaxf(x, __int_as_float(t));
    t = __builtin_amdgcn_update_dpp(0, __float_as_int(x), 0x128, 0xF, 0xF, false);
    x = fmaxf(x, __int_as_float(t));
    return x;
}

// ---------------------------------------------------------------- init: zero the histogram
__global__ __launch_bounds__(256) void init_kernel(int* __restrict__ count)
{
    int i = blockIdx.x * 256 + threadIdx.x;
    if (i < N_NODES) count[i] = 0;
}

// ---------------------------------------------------------------- layer1 node projections
#define P1_NB 16
__global__ __launch_bounds__(64) void proj1_kernel(
    const float* __restrict__ x,
    const float* __restrict__ Wq, const float* __restrict__ bq,
    const float* __restrict__ Wk, const float* __restrict__ bk,
    const float* __restrict__ Wv, const float* __restrict__ bv,
    const float* __restrict__ Ws, const float* __restrict__ bs,
    float* __restrict__ q1, float* __restrict__ k1,
    float* __restrict__ v1, float* __restrict__ s1)
{
    __shared__ float xs[P1_NB][IN_F];
    const int t  = threadIdx.x;          // 0..63 = output column
    const int n0 = blockIdx.x * P1_NB;

    for (int j = t; j < P1_NB * IN_F; j += 64)
        xs[j >> 7][j & 127] = x[(size_t)n0 * IN_F + j];
    __syncthreads();

    float aq[P1_NB], ak[P1_NB], av[P1_NB], as_[P1_NB];
#pragma unroll
    for (int n = 0; n < P1_NB; n++) { aq[n] = ak[n] = av[n] = as_[n] = 0.f; }

    for (int i = 0; i < IN_F; i++) {
        float wq = Wq[i * HC + t];
        float wk = Wk[i * HC + t];
        float wv = Wv[i * HC + t];
        float ws = Ws[i * HC + t];
#pragma unroll
        for (int n = 0; n < P1_NB; n++) {
            float xv = xs[n][i];
            aq[n] += xv * wq; ak[n] += xv * wk;
            av[n] += xv * wv; as_[n] += xv * ws;
        }
    }
    float bqv = bq[t], bkv = bk[t], bvv = bv[t], bsv = bs[t];
#pragma unroll
    for (int n = 0; n < P1_NB; n++) {
        size_t o = (size_t)(n0 + n) * HC + t;
        q1[o] = aq[n] + bqv; k1[o] = ak[n] + bkv;
        v1[o] = av[n] + bvv; s1[o] = as_[n] + bsv;
    }
}

// ---------------------------------------------------------------- histogram of dst
__global__ __launch_bounds__(256) void hist_kernel(
    const int* __restrict__ ei, int* __restrict__ count)
{
    int e = blockIdx.x * 256 + threadIdx.x;
    if (e < N_EDGES) atomicAdd(count + ei[N_EDGES + e], 1);
}

// ---------------------------------------------------------------- scan phase 1
__global__ __launch_bounds__(256) void scan1_kernel(
    const int* __restrict__ count, int* __restrict__ pre, int* __restrict__ bsum)
{
    __shared__ int sdata[256];
    const int t = threadIdx.x;
    const int i = blockIdx.x * 256 + t;
    int v = (i < N_NODES) ? count[i] : 0;
    sdata[t] = v;
    __syncthreads();
    for (int d = 1; d < 256; d <<= 1) {
        int u = (t >= d) ? sdata[t - d] : 0;
        __syncthreads();
        sdata[t] += u;
        __syncthreads();
    }
    if (i < N_NODES) pre[i] = sdata[t] - v;
    if (t == 255) bsum[blockIdx.x] = sdata[255];
}

// ---------------------------------------------------------------- scan phase 2 (1 block)
__global__ __launch_bounds__(256) void scan2_kernel(
    int* __restrict__ bsum, int* __restrict__ bofs)
{
    __shared__ int sdata[256];
    const int t = threadIdx.x;
    int v = (t < NSB) ? bsum[t] : 0;
    sdata[t] = v;
    __syncthreads();
    for (int d = 1; d < 256; d <<= 1) {
        int u = (t >= d) ? sdata[t - d] : 0;
        __syncthreads();
        sdata[t] += u;
        __syncthreads();
    }
    if (t < NSB) bofs[t] = sdata[t] - v;
}

// ---------------------------------------------------------------- scan phase 3
__global__ __launch_bounds__(256) void scan3_kernel(
    const int* __restrict__ pre, const int* __restrict__ bofs,
    int* __restrict__ offs, int* __restrict__ cursor)
{
    const int i = blockIdx.x * 256 + threadIdx.x;
    if (i < N_NODES) {
        int o = pre[i] + bofs[i >> 8];
        offs[i] = o; cursor[i] = o;
    }
    if (i == 0) offs[N_NODES] = N_EDGES;
}

// ---------------------------------------------------------------- scatter: one packed 16B record per edge
__global__ __launch_bounds__(256) void scatter_kernel(
    const int* __restrict__ ei, const float* __restrict__ ea,
    int* __restrict__ cursor, float4* __restrict__ erec)
{
    int e = blockIdx.x * 256 + threadIdx.x;
    if (e >= N_EDGES) return;
    int dst = ei[N_EDGES + e];
    int pos = atomicAdd(cursor + dst, 1);
    float4 r;
    r.x = __int_as_float(ei[e]);
    r.y = ea[(size_t)e * 2];
    r.z = ea[(size_t)e * 2 + 1];
    r.w = 0.f;
    erec[pos] = r;
}

// ---------------------------------------------------------------- layer1 attention: one wave per dst node
__global__ __launch_bounds__(256) void attn1_kernel(
    const int* __restrict__ offs, const float4* __restrict__ erec,
    const float* __restrict__ We,
    const float* __restrict__ q1, const float* __restrict__ k1,
    const float* __restrict__ v1, const float* __restrict__ s1,
    float* __restrict__ h)
{
    int n    = (blockIdx.x * 256 + threadIdx.x) >> 6;
    int lane = threadIdx.x & 63;
    if (n >= N_NODES) return;

    float qv  = q1[(size_t)n * HC + lane];
    float We0 = We[lane], We1 = We[HC + lane];
    int beg = offs[n], end = offs[n + 1];

    float m = -3.402823466e38f, l = 0.f, acc = 0.f;
    int i = beg;
    for (; i + 1 < end; i += 2) {
        float4 r0 = erec[i], r1 = erec[i + 1];
        int s0 = __float_as_int(r0.x), s1v = __float_as_int(r1.x);
        float ec0 = r0.y * We0 + r0.z * We1;
        float ec1 = r1.y * We0 + r1.z * We1;
        size_t b0 = (size_t)s0 * HC + lane, b1 = (size_t)s1v * HC + lane;
        float k0 = k1[b0] + ec0, k1v = k1[b1] + ec1;
        float v0 = v1[b0] + ec0, v1r = v1[b1] + ec1;
        float p0 = dpp_add16(qv * k0) * 0.25f;       // 1/sqrt(16)
        float p1 = dpp_add16(qv * k1v) * 0.25f;
        float mn = fmaxf(m, fmaxf(p0, p1));
        float sm = __expf(m - mn);
        float e0 = __expf(p0 - mn);
        float e1 = __expf(p1 - mn);
        l   = l   * sm + e0 + e1;
        acc = acc * sm + e0 * v0 + e1 * v1r;
        m = mn;
    }
    if (i < end) {
        float4 r0 = erec[i];
        int s0 = __float_as_int(r0.x);
        float ec0 = r0.y * We0 + r0.z * We1;
        size_t b0 = (size_t)s0 * HC + lane;
        float k0 = k1[b0] + ec0;
        float v0 = v1[b0] + ec0;
        float p0 = dpp_add16(qv * k0) * 0.25f;
        float mn = fmaxf(m, p0);
        float sm = __expf(m - mn);
        float e0 = __expf(p0 - mn);
        l   = l   * sm + e0;
        acc = acc * sm + e0 * v0;
        m = mn;
    }
    float att = (end > beg) ? acc / l : 0.f;
    float o = att + s1[(size_t)n * HC + lane];
    h[(size_t)n * HC + lane] = o > 0.f ? o : expm1f(o);   // ELU fused
}

// ---------------------------------------------------------------- layer2 node projections (64 -> 28), thread-per-node
// W staged in LDS as [64][4][8] (c padded to 8, pad=0). Each thread: 16x
// float4 h loads, 32 accumulators, 2048 ILP FMAs. Outputs padded/interleaved.
__global__ __launch_bounds__(256) void proj2_kernel(
    const float* __restrict__ h,
    const float* __restrict__ Wq, const float* __restrict__ bq,
    const float* __restrict__ Wk, const float* __restrict__ bk,
    const float* __restrict__ Wv, const float* __restrict__ bv,
    const float* __restrict__ Ws, const float* __restrict__ bs,
    float* __restrict__ q2p, float* __restrict__ kv2, float* __restrict__ s2p)
{
    __shared__ float Wsm[HC][4][8];   // 8 KB
    __shared__ float Bsm[4][8];
    const int t = threadIdx.x;

    for (int j = t; j < HC * 28; j += 256) {
        int i = j / 28, r = j % 28, mtx = r / 7, c = r % 7;
        const float* W = (mtx == 0) ? Wq : (mtx == 1) ? Wk : (mtx == 2) ? Wv : Ws;
        Wsm[i][mtx][c] = W[i * OUTF + c];
    }
    for (int j = t; j < HC * 4; j += 256)          // zero the c=7 pad
        Wsm[j >> 2][j & 3][7] = 0.f;
    if (t < 32) {
        int mtx = t >> 3, c = t & 7;
        const float* B = (mtx == 0) ? bq : (mtx == 1) ? bk : (mtx == 2) ? bv : bs;
        Bsm[mtx][c] = (c < 7) ? B[c] : 0.f;
    }
    __syncthreads();

    int n = blockIdx.x * 256 + t;
    if (n >= N_NODES) return;

    float acc[4][8];
#pragma unroll
    for (int mtx = 0; mtx < 4; mtx++)
#pragma unroll
        for (int c = 0; c < 8; c++) acc[mtx][c] = Bsm[mtx][c];

    const float4* hp = (const float4*)(h + (size_t)n * HC);
#pragma unroll 4
    for (int i4 = 0; i4 < 16; i4++) {
        float4 hv = hp[i4];
        float hx[4] = { hv.x, hv.y, hv.z, hv.w };
#pragma unroll
        for (int e = 0; e < 4; e++) {
            int i = i4 * 4 + e;
#pragma unroll
            for (int mtx = 0; mtx < 4; mtx++) {
                float4 wa = *(const float4*)&Wsm[i][mtx][0];
                float4 wb = *(const float4*)&Wsm[i][mtx][4];
                acc[mtx][0] += hx[e] * wa.x; acc[mtx][1] += hx[e] * wa.y;
                acc[mtx][2] += hx[e] * wa.z; acc[mtx][3] += hx[e] * wa.w;
                acc[mtx][4] += hx[e] * wb.x; acc[mtx][5] += hx[e] * wb.y;
                acc[mtx][6] += hx[e] * wb.z; acc[mtx][7] += hx[e] * wb.w;
            }
        }
    }

    float4* q2v = (float4*)(q2p + (size_t)n * 8);
    q2v[0] = make_float4(acc[0][0], acc[0][1], acc[0][2], acc[0][3]);
    q2v[1] = make_float4(acc[0][4], acc[0][5], acc[0][6], acc[0][7]);
    float4* kvv = (float4*)(kv2 + (size_t)n * 16);
    kvv[0] = make_float4(acc[1][0], acc[1][1], acc[1][2], acc[1][3]);
    kvv[1] = make_float4(acc[1][4], acc[1][5], acc[1][6], acc[1][7]);
    kvv[2] = make_float4(acc[2][0], acc[2][1], acc[2][2], acc[2][3]);
    kvv[3] = make_float4(acc[2][4], acc[2][5], acc[2][6], acc[2][7]);
    float4* s2v = (float4*)(s2p + (size_t)n * 8);
    s2v[0] = make_float4(acc[3][0], acc[3][1], acc[3][2], acc[3][3]);
    s2v[1] = make_float4(acc[3][4], acc[3][5], acc[3][6], acc[3][7]);
}

// ---------------------------------------------------------------- layer2 attention: one wave per dst node
__global__ __launch_bounds__(256) void attn2_kernel(
    const int* __restrict__ offs, const float4* __restrict__ erec,
    const float* __restrict__ q2p, const float* __restrict__ kv2,
    const float* __restrict__ s2p, float* __restrict__ out)
{
    int n    = (blockIdx.x * 256 + threadIdx.x) >> 6;
    int lane = threadIdx.x & 63;
    if (n >= N_NODES) return;

    float4 qa = *(const float4*)(q2p + (size_t)n * 8);
    float4 qb = *(const float4*)(q2p + (size_t)n * 8 + 4);
    int beg = offs[n], end = offs[n + 1];

    float m = -3.402823466e38f, l = 0.f, a[OUTF];
#pragma unroll
    for (int c = 0; c < OUTF; c++) a[c] = 0.f;

    for (int i = beg + lane; i < end; i += 64) {
        int src = __float_as_int(erec[i].x);
        const float4* kvp = (const float4*)(kv2 + (size_t)src * 16);
        float4 ka = kvp[0], kb = kvp[1], va = kvp[2], vb = kvp[3];
        float dot = qa.x * ka.x + qa.y * ka.y + qa.z * ka.z + qa.w * ka.w
                  + qb.x * kb.x + qb.y * kb.y + qb.z * kb.z;
        float logit = dot * 0.37796447300922725f;       // 1/sqrt(7)
        float mn = fmaxf(m, logit);
        float sc = __expf(m - mn);
        float pe = __expf(logit - mn);
        l = l * sc + pe;
        a[0] = a[0] * sc + pe * va.x;
        a[1] = a[1] * sc + pe * va.y;
        a[2] = a[2] * sc + pe * va.z;
        a[3] = a[3] * sc + pe * va.w;
        a[4] = a[4] * sc + pe * vb.x;
        a[5] = a[5] * sc + pe * vb.y;
        a[6] = a[6] * sc + pe * vb.z;
        m = mn;
    }

    if (end > beg) {
        float M = dpp_max16(m);
        M = fmaxf(M, __shfl_xor(M, 16));
        M = fmaxf(M, __shfl_xor(M, 32));
        float sc = __expf(m - M);
        l *= sc;
#pragma unroll
        for (int c = 0; c < OUTF; c++) a[c] *= sc;
        l = dpp_add16(l); l += __shfl_xor(l, 16); l += __shfl_xor(l, 32);
#pragma unroll
        for (int c = 0; c < OUTF; c++) {
            float t = dpp_add16(a[c]);
            t += __shfl_xor(t, 16); t += __shfl_xor(t, 32);
            a[c] = t;
        }
        if (lane == 0) {
            float inv = 1.f / fmaxf(l, 1e-16f);
#pragma unroll
            for (int c = 0; c < OUTF; c++)
                out[(size_t)n * OUTF + c] = a[c] * inv + s2p[(size_t)n * 8 + c];
        }
    } else if (lane == 0) {
#pragma unroll
        for (int c = 0; c < OUTF; c++)
            out[(size_t)n * OUTF + c] = s2p[(size_t)n * 8 + c];
    }
}

// ----------------------------------------------------------------
extern "C" void kernel_launch(void* const* d_in, const int* in_sizes, int n_in,
                              void* d_out, int out_size, void* d_ws, size_t ws_size,
                              hipStream_t stream)
{
    const float* x    = (const float*)d_in[0];
    const float* ea   = (const float*)d_in[1];
    const int*   ei   = (const int*)d_in[2];
    const float* Wq1  = (const float*)d_in[3];
    const float* bq1  = (const float*)d_in[4];
    const float* Wk1  = (const float*)d_in[5];
    const float* bk1  = (const float*)d_in[6];
    const float* Wv1  = (const float*)d_in[7];
    const float* bv1  = (const float*)d_in[8];
    const float* We1  = (const float*)d_in[9];
    const float* Ws1  = (const float*)d_in[10];
    const float* bs1  = (const float*)d_in[11];
    const float* Wq2  = (const float*)d_in[12];
    const float* bq2  = (const float*)d_in[13];
    const float* Wk2  = (const float*)d_in[14];
    const float* bk2  = (const float*)d_in[15];
    const float* Wv2  = (const float*)d_in[16];
    const float* bv2  = (const float*)d_in[17];
    const float* Ws2  = (const float*)d_in[18];
    const float* bs2  = (const float*)d_in[19];
    float* out = (float*)d_out;

    // workspace layout (f32 words), ~84 MB total; all segments 16B-aligned.
    float* ws = (float*)d_ws;
    float*  q1   = ws;                               // N*64
    float*  k1   = q1 + (size_t)N_NODES * HC;
    float*  v1   = k1 + (size_t)N_NODES * HC;
    float*  s1   = v1 + (size_t)N_NODES * HC;
    float*  hbuf = q1;                               // alias: attn1 reads q1[slot] then writes h[slot]
    float4* erec = (float4*)(s1 + (size_t)N_NODES * HC);    // E x 16B
    float*  q2p  = (float*)(erec + N_EDGES);         // N*8
    float*  kv2  = q2p + (size_t)N_NODES * 8;        // N*16
    float*  s2p  = kv2 + (size_t)N_NODES * 16;       // N*8
    int*    count  = (int*)(s2p + (size_t)N_NODES * 8);     // N
    int*    offs   = count + N_NODES;                // N+1
    int*    cursor = offs + N_NODES + 1;             // N
    int*    pre    = cursor + N_NODES;               // N
    int*    bsum   = pre + N_NODES;                  // NSB
    int*    bofs   = bsum + NSB;                     // NSB

    const int eb = (N_EDGES + 255) / 256;
    const int nwave_blocks = (N_NODES * 64 + 255) / 256;

    init_kernel<<<(N_NODES + 255) / 256, 256, 0, stream>>>(count);

    proj1_kernel<<<N_NODES / P1_NB, 64, 0, stream>>>(
        x, Wq1, bq1, Wk1, bk1, Wv1, bv1, Ws1, bs1, q1, k1, v1, s1);

    hist_kernel<<<eb, 256, 0, stream>>>(ei, count);
    scan1_kernel<<<NSB, 256, 0, stream>>>(count, pre, bsum);
    scan2_kernel<<<1, 256, 0, stream>>>(bsum, bofs);
    scan3_kernel<<<NSB, 256, 0, stream>>>(pre, bofs, offs, cursor);
    scatter_kernel<<<eb, 256, 0, stream>>>(ei, ea, cursor, erec);

    attn1_kernel<<<nwave_blocks, 256, 0, stream>>>(
        offs, erec, We1, q1, k1, v1, s1, hbuf);

    proj2_kernel<<<(N_NODES + 255) / 256, 256, 0, stream>>>(
        hbuf, Wq2, bq2, Wk2, bk2, Wv2, bv2, Ws2, bs2, q2p, kv2, s2p);

    attn2_kernel<<<nwave_blocks, 256, 0, stream>>>(
        offs, erec, q2p, kv2, s2p, out);
}